// Round 4
// baseline (232.826 us; speedup 1.0000x reference)
//
#include <hip/hip_runtime.h>
#include <hip/hip_bf16.h>

#define B_ 128
#define S_ 200
#define QN_ 20000
#define V_ 128
#define K_ 128
#define C_ 64
#define SUM_ 128
#define P1P 16   // positions per phase1 block

// ---- dtype-generic loads (BF=true: bf16, BF=false: fp32) ----
template<bool BF>
__device__ __forceinline__ float ld(const void* p, long long i) {
    if (BF) return __bfloat162float(((const __hip_bfloat16*)p)[i]);
    return ((const float*)p)[i];
}
template<bool BF>
__device__ __forceinline__ float2 ld2(const void* p, long long i) {  // elems 2i, 2i+1
    if (BF) {
        __hip_bfloat162 v = ((const __hip_bfloat162*)p)[i];
        return make_float2(__bfloat162float(v.x), __bfloat162float(v.y));
    }
    return ((const float2*)p)[i];
}
// 16 consecutive elements starting at elem offset off (off must be mult. of 16)
template<bool BF>
__device__ __forceinline__ void ld16(const void* p, long long off, float* out) {
    if (BF) {
        const uint4* q = (const uint4*)((const unsigned short*)p + off);
        uint4 u0 = q[0], u1 = q[1];
        unsigned uu[8] = {u0.x, u0.y, u0.z, u0.w, u1.x, u1.y, u1.z, u1.w};
        #pragma unroll
        for (int k = 0; k < 8; ++k) {
            out[2 * k]     = __uint_as_float(uu[k] << 16);
            out[2 * k + 1] = __uint_as_float(uu[k] & 0xffff0000u);
        }
    } else {
        const float4* q = (const float4*)((const float*)p + off);
        float4 f0 = q[0], f1 = q[1], f2 = q[2], f3 = q[3];
        out[0]=f0.x; out[1]=f0.y; out[2]=f0.z; out[3]=f0.w;
        out[4]=f1.x; out[5]=f1.y; out[6]=f1.z; out[7]=f1.w;
        out[8]=f2.x; out[9]=f2.y; out[10]=f2.z; out[11]=f2.w;
        out[12]=f3.x; out[13]=f3.y; out[14]=f3.z; out[15]=f3.w;
    }
}

// ---- dtype probe, computed per-block (no separate dispatch) ----
// erase_b: 128 elements, |x| <= 1/sqrt(128). bf16 data: low 16 bits of each
// u32 = small bf16. fp32 data: low 16 bits = random mantissa -> wild bf16.
__device__ __forceinline__ int probe_flag(const void* erase_b) {
    const unsigned* w = (const unsigned*)erase_b;
    int bad = 0;
    #pragma unroll 8
    for (int i = 0; i < 64; ++i) {
        unsigned lo = w[i] & 0xffffu;
        float f = __uint_as_float(lo << 16);
        if (!(fabsf(f) <= 0.5f)) bad++;  // NaN also fails
    }
    return (bad <= 8) ? 1 : 0;  // 1 = bf16
}

// ================= Phase 1: batched mat-vecs, P=16 positions/block =================
template<bool BF>
__device__ __forceinline__ void phase1_body(
    const void* q_emb, const void* i_emb, const void* key_memory,
    const void* erase_W, const void* erase_b, const void* add_W, const void* add_b,
    const int* __restrict__ input,
    float* __restrict__ e_buf, float* __restrict__ a_buf, float* __restrict__ w_buf,
    float* ivT, float* qvT, int* sidx, int* sqid)
{
    const int p0 = blockIdx.x * P1P;
    const int t = threadIdx.x;  // 0..191

    if (t < P1P) {
        const int ix = input[p0 + t];
        sidx[t] = ix;
        sqid[t] = ix > QN_ ? ix - QN_ : ix;
    }
    __syncthreads();

    // stage 256 jobs: (tensor, p, 16-elem segment) -> transposed LDS
    for (int rep = 0; rep < 2; ++rep) {
        const int j = (rep == 0) ? t : t + 192;
        if (j < 256) {
            const int tensor = j >> 7;
            const int r = j & 127;
            const int p = r >> 3;
            const int i0 = (r & 7) * 16;
            const int row = tensor ? sqid[p] : sidx[p];
            const void* src = tensor ? q_emb : i_emb;
            float* dst = tensor ? qvT : ivT;
            float x[16];
            ld16<BF>(src, (long long)row * 128 + i0, x);
            #pragma unroll
            for (int k = 0; k < 16; ++k)
                dst[(i0 + k) * 16 + p] = x[k];
        }
    }
    __syncthreads();

    const int g = t >> 6;    // 0=erase cols, 1=add cols, 2=w logits
    const int c = t & 63;

    if (g < 2) {
        const void* W = g ? add_W : erase_W;
        const float2 bb = ld2<BF>(g ? add_b : erase_b, c);
        float acc0[P1P], acc1[P1P];
        #pragma unroll
        for (int p = 0; p < P1P; ++p) { acc0[p] = bb.x; acc1[p] = bb.y; }

        #pragma unroll 8
        for (int i = 0; i < 128; ++i) {
            const float2 wv = ld2<BF>(W, i * 64 + c);     // cols 2c,2c+1 of row i
            const float4* ivr = (const float4*)&ivT[i * 16];
            const float4 x0 = ivr[0], x1 = ivr[1], x2 = ivr[2], x3 = ivr[3];
            const float xx[16] = {x0.x,x0.y,x0.z,x0.w, x1.x,x1.y,x1.z,x1.w,
                                  x2.x,x2.y,x2.z,x2.w, x3.x,x3.y,x3.z,x3.w};
            #pragma unroll
            for (int p = 0; p < P1P; ++p) {
                acc0[p] += xx[p] * wv.x;
                acc1[p] += xx[p] * wv.y;
            }
        }
        if (g == 0) {
            #pragma unroll
            for (int p = 0; p < P1P; ++p) {
                const float o0 = 1.f / (1.f + expf(-acc0[p]));
                const float o1 = 1.f / (1.f + expf(-acc1[p]));
                ((float2*)(e_buf + (size_t)(p0 + p) * V_))[c] = make_float2(o0, o1);
            }
        } else {
            #pragma unroll
            for (int p = 0; p < P1P; ++p)
                ((float2*)(a_buf + (size_t)(p0 + p) * V_))[c] =
                    make_float2(tanhf(acc0[p]), tanhf(acc1[p]));
        }
    } else {
        float acc[P1P];
        #pragma unroll
        for (int p = 0; p < P1P; ++p) acc[p] = 0.f;
        #pragma unroll 8
        for (int i = 0; i < 128; ++i) {
            const float kv = ld<BF>(key_memory, i * C_ + c);
            const float4* qvr = (const float4*)&qvT[i * 16];
            const float4 x0 = qvr[0], x1 = qvr[1], x2 = qvr[2], x3 = qvr[3];
            const float xx[16] = {x0.x,x0.y,x0.z,x0.w, x1.x,x1.y,x1.z,x1.w,
                                  x2.x,x2.y,x2.z,x2.w, x3.x,x3.y,x3.z,x3.w};
            #pragma unroll
            for (int p = 0; p < P1P; ++p) acc[p] += xx[p] * kv;
        }
        #pragma unroll
        for (int p = 0; p < P1P; ++p) {
            float m = acc[p];
            for (int off = 32; off > 0; off >>= 1)
                m = fmaxf(m, __shfl_xor(m, off, 64));
            const float ex = expf(acc[p] - m);
            float ssum = ex;
            for (int off = 32; off > 0; off >>= 1)
                ssum += __shfl_xor(ssum, off, 64);
            w_buf[(size_t)(p0 + p) * C_ + c] = ex / ssum;
        }
    }
}

__global__ __launch_bounds__(192) void dkvmn_phase1(
    const void* q_emb, const void* i_emb, const void* key_memory,
    const void* erase_W, const void* erase_b, const void* add_W, const void* add_b,
    const int* __restrict__ input,
    float* e_buf, float* a_buf, float* w_buf)
{
    __shared__ float ivT[128 * P1P];
    __shared__ float qvT[128 * P1P];
    __shared__ int sidx[P1P], sqid[P1P];
    __shared__ int sflag;
    if (threadIdx.x == 0) sflag = probe_flag(erase_b);
    __syncthreads();
    if (sflag)
        phase1_body<true>(q_emb, i_emb, key_memory, erase_W, erase_b, add_W, add_b,
                          input, e_buf, a_buf, w_buf, ivT, qvT, sidx, sqid);
    else
        phase1_body<false>(q_emb, i_emb, key_memory, erase_W, erase_b, add_W, add_b,
                           input, e_buf, a_buf, w_buf, ivT, qvT, sidx, sqid);
}

// ====== Phase 2: register scan, 1 wave / (b, 4-v group), XCD-affine, 4-deep pipe ======
template<bool BF>
__device__ __forceinline__ void phase2_body(
    const void* q_emb, const void* key_memory, const void* init_value_memory,
    const int* __restrict__ target_id,
    const float* __restrict__ e_buf, const float* __restrict__ a_buf,
    const float* __restrict__ w_buf, float* __restrict__ read_buf)
{
    // XCD-affinity swizzle: blocks land on XCD (bid & 7) under round-robin
    // dispatch; give each XCD 16 whole batches so w/e/a lines are fetched
    // into exactly one per-XCD L2.
    const int bid = blockIdx.x;
    const int x = bid & 7;
    const int j = bid >> 3;          // 0..511
    const int b = x * 16 + (j >> 5); // 16 batches per XCD
    const int vg = j & 31;           // v = vg*4 + k
    const int c = threadIdx.x;       // 0..63

    float mem[4];
    #pragma unroll
    for (int k = 0; k < 4; ++k)
        mem[k] = ld<BF>(init_value_memory, (vg * 4 + k) * C_ + c);

    const float* eb = e_buf + (size_t)b * S_ * V_ + vg * 4;
    const float* ab = a_buf + (size_t)b * S_ * V_ + vg * 4;
    const float* wb = w_buf + (size_t)b * S_ * C_ + c;

    // 4-step software pipeline: 12 loads in flight
    float4 pe[4], pa[4];
    float pw[4];
    #pragma unroll
    for (int k = 0; k < 4; ++k) {
        pe[k] = *(const float4*)(eb + (size_t)k * V_);
        pa[k] = *(const float4*)(ab + (size_t)k * V_);
        pw[k] = wb[(size_t)k * C_];
    }
    for (int s0 = 0; s0 < S_; s0 += 4) {
        #pragma unroll
        for (int k = 0; k < 4; ++k) {
            const float4 e4 = pe[k], a4 = pa[k];
            const float wv = pw[k];
            const int sn = s0 + k + 4;
            if (sn < S_) {
                pe[k] = *(const float4*)(eb + (size_t)sn * V_);
                pa[k] = *(const float4*)(ab + (size_t)sn * V_);
                pw[k] = wb[(size_t)sn * C_];
            }
            // mem = mem*(1 - e*w) + a*w == mem + w*(a - mem*e)
            mem[0] = fmaf(wv, fmaf(-mem[0], e4.x, a4.x), mem[0]);
            mem[1] = fmaf(wv, fmaf(-mem[1], e4.y, a4.y), mem[1]);
            mem[2] = fmaf(wv, fmaf(-mem[2], e4.z, a4.z), mem[2]);
            mem[3] = fmaf(wv, fmaf(-mem[3], e4.w, a4.w), mem[3]);
        }
    }

    // wt = softmax_c(qv @ key_memory), computed redundantly per block
    const long long qrow = (long long)target_id[b] * K_;
    float logit = 0.f;
    #pragma unroll 8
    for (int i = 0; i < K_; ++i)
        logit += ld<BF>(q_emb, qrow + i) * ld<BF>(key_memory, i * C_ + c);
    float m = logit;
    for (int off = 32; off > 0; off >>= 1)
        m = fmaxf(m, __shfl_xor(m, off, 64));
    const float ex = expf(logit - m);
    float ssum = ex;
    for (int off = 32; off > 0; off >>= 1)
        ssum += __shfl_xor(ssum, off, 64);
    const float wt = ex / ssum;

    #pragma unroll
    for (int k = 0; k < 4; ++k) {
        float r = mem[k] * wt;
        for (int off = 32; off > 0; off >>= 1)
            r += __shfl_xor(r, off, 64);
        if (c == 0) read_buf[b * V_ + vg * 4 + k] = r;
    }
}

__global__ __launch_bounds__(64) void dkvmn_phase2(
    const void* q_emb, const void* key_memory, const void* init_value_memory,
    const void* erase_b,
    const int* __restrict__ target_id,
    const float* e_buf, const float* a_buf, const float* w_buf,
    float* read_buf)
{
    __shared__ int sflag;
    if (threadIdx.x == 0) sflag = probe_flag(erase_b);
    __syncthreads();
    if (sflag)
        phase2_body<true>(q_emb, key_memory, init_value_memory, target_id,
                          e_buf, a_buf, w_buf, read_buf);
    else
        phase2_body<false>(q_emb, key_memory, init_value_memory, target_id,
                           e_buf, a_buf, w_buf, read_buf);
}

// ================= Phase 3: summ mat-vec + scalar out =================
template<bool BF>
__device__ __forceinline__ void phase3_body(
    const void* q_emb, const void* summ_W, const void* summ_b,
    const void* out_W, const void* out_b,
    const int* __restrict__ target_id, const float* __restrict__ read_buf,
    void* outp, float* summl)
{
    const int b = blockIdx.x;
    const int t = threadIdx.x;  // 0..127
    const long long qrow = (long long)target_id[b] * K_;

    float acc = ld<BF>(summ_b, t);
    #pragma unroll 8
    for (int i = 0; i < 128; ++i)
        acc += read_buf[b * V_ + i] * ld<BF>(summ_W, i * SUM_ + t);
    #pragma unroll 8
    for (int i = 0; i < 128; ++i)
        acc += ld<BF>(q_emb, qrow + i) * ld<BF>(summ_W, (128 + i) * SUM_ + t);
    summl[t] = tanhf(acc);
    __syncthreads();

    if (t < 64) {
        float pacc = summl[t] * ld<BF>(out_W, t) + summl[t + 64] * ld<BF>(out_W, t + 64);
        for (int off = 32; off > 0; off >>= 1)
            pacc += __shfl_xor(pacc, off, 64);
        if (t == 0) {
            const float res = pacc + ld<BF>(out_b, 0);
            if (BF) ((__hip_bfloat16*)outp)[b] = __float2bfloat16(res);
            else    ((float*)outp)[b] = res;
        }
    }
}

__global__ __launch_bounds__(128) void dkvmn_phase3(
    const void* q_emb, const void* summ_W, const void* summ_b,
    const void* out_W, const void* out_b, const void* erase_b,
    const int* __restrict__ target_id, const float* read_buf,
    void* outp)
{
    __shared__ float summl[SUM_];
    __shared__ int sflag;
    if (threadIdx.x == 0) sflag = probe_flag(erase_b);
    __syncthreads();
    if (sflag)
        phase3_body<true>(q_emb, summ_W, summ_b, out_W, out_b, target_id,
                          read_buf, outp, summl);
    else
        phase3_body<false>(q_emb, summ_W, summ_b, out_W, out_b, target_id,
                           read_buf, outp, summl);
}

extern "C" void kernel_launch(void* const* d_in, const int* in_sizes, int n_in,
                              void* d_out, int out_size, void* d_ws, size_t ws_size,
                              hipStream_t stream) {
    const void* q_emb             = d_in[0];
    const void* i_emb             = d_in[1];
    const void* key_memory        = d_in[2];
    const void* init_value_memory = d_in[3];
    const void* erase_W           = d_in[4];
    const void* erase_b           = d_in[5];
    const void* add_W             = d_in[6];
    const void* add_b             = d_in[7];
    const void* summ_W            = d_in[8];
    const void* summ_b            = d_in[9];
    const void* out_W             = d_in[10];
    const void* out_b             = d_in[11];
    const int* input     = (const int*)d_in[12];
    const int* target_id = (const int*)d_in[13];

    // ws: [e B*S*V f32][a B*S*V f32][w B*S*C f32][read B*V f32]
    float* e_buf    = (float*)d_ws;
    float* a_buf    = e_buf + (size_t)B_ * S_ * V_;
    float* w_buf    = a_buf + (size_t)B_ * S_ * V_;
    float* read_buf = w_buf + (size_t)B_ * S_ * C_;

    dkvmn_phase1<<<(B_ * S_) / P1P, 192, 0, stream>>>(
        q_emb, i_emb, key_memory, erase_W, erase_b, add_W, add_b,
        input, e_buf, a_buf, w_buf);
    dkvmn_phase2<<<B_ * 32, 64, 0, stream>>>(
        q_emb, key_memory, init_value_memory, erase_b, target_id,
        e_buf, a_buf, w_buf, read_buf);
    dkvmn_phase3<<<B_, 128, 0, stream>>>(
        q_emb, summ_W, summ_b, out_W, out_b, erase_b, target_id, read_buf, d_out);
}

// Round 6
// 230.718 us; speedup vs baseline: 1.0091x; 1.0091x over previous
//
#include <hip/hip_runtime.h>
#include <hip/hip_bf16.h>

#define B_ 128
#define S_ 200
#define QN_ 20000
#define V_ 128
#define K_ 128
#define C_ 64
#define SUM_ 128
#define P1P 16   // positions per phase1 block

// ---- dtype-generic loads (BF=true: bf16, BF=false: fp32) ----
template<bool BF>
__device__ __forceinline__ float ld(const void* p, long long i) {
    if (BF) return __bfloat162float(((const __hip_bfloat16*)p)[i]);
    return ((const float*)p)[i];
}
template<bool BF>
__device__ __forceinline__ float2 ld2(const void* p, long long i) {  // elems 2i, 2i+1
    if (BF) {
        __hip_bfloat162 v = ((const __hip_bfloat162*)p)[i];
        return make_float2(__bfloat162float(v.x), __bfloat162float(v.y));
    }
    return ((const float2*)p)[i];
}
// 16 consecutive elements starting at elem offset off (off must be mult. of 16)
template<bool BF>
__device__ __forceinline__ void ld16(const void* p, long long off, float* out) {
    if (BF) {
        const uint4* q = (const uint4*)((const unsigned short*)p + off);
        uint4 u0 = q[0], u1 = q[1];
        unsigned uu[8] = {u0.x, u0.y, u0.z, u0.w, u1.x, u1.y, u1.z, u1.w};
        #pragma unroll
        for (int k = 0; k < 8; ++k) {
            out[2 * k]     = __uint_as_float(uu[k] << 16);
            out[2 * k + 1] = __uint_as_float(uu[k] & 0xffff0000u);
        }
    } else {
        const float4* q = (const float4*)((const float*)p + off);
        float4 f0 = q[0], f1 = q[1], f2 = q[2], f3 = q[3];
        out[0]=f0.x; out[1]=f0.y; out[2]=f0.z; out[3]=f0.w;
        out[4]=f1.x; out[5]=f1.y; out[6]=f1.z; out[7]=f1.w;
        out[8]=f2.x; out[9]=f2.y; out[10]=f2.z; out[11]=f2.w;
        out[12]=f3.x; out[13]=f3.y; out[14]=f3.z; out[15]=f3.w;
    }
}

// opaque zero in a VGPR: makes addresses look lane-varying so the compiler
// emits vector global_loads (vmcnt-tracked, pipelinable) instead of scalar
// s_loads (whose smem returns force lgkmcnt(0) drains -> serialized pipe).
__device__ __forceinline__ int opaque_zero() {
    int z;
    asm volatile("v_mov_b32 %0, 0" : "=v"(z));
    return z;
}

// ---- dtype probe, computed per-block (no separate dispatch) ----
// erase_b: 128 elements, |x| <= 1/sqrt(128). bf16 data: low 16 bits of each
// u32 = small bf16. fp32 data: low 16 bits = random mantissa -> wild bf16.
__device__ __forceinline__ int probe_flag(const void* erase_b) {
    const unsigned* w = (const unsigned*)erase_b;
    int bad = 0;
    #pragma unroll 8
    for (int i = 0; i < 64; ++i) {
        unsigned lo = w[i] & 0xffffu;
        float f = __uint_as_float(lo << 16);
        if (!(fabsf(f) <= 0.5f)) bad++;  // NaN also fails
    }
    return (bad <= 8) ? 1 : 0;  // 1 = bf16
}

// ================= Phase 1: batched mat-vecs, P=16 positions/block =================
template<bool BF>
__device__ __forceinline__ void phase1_body(
    const void* q_emb, const void* i_emb, const void* key_memory,
    const void* erase_W, const void* erase_b, const void* add_W, const void* add_b,
    const int* __restrict__ input,
    float* __restrict__ e_buf, float* __restrict__ a_buf, float* __restrict__ w_buf,
    float* ivT, float* qvT, int* sidx, int* sqid)
{
    const int p0 = blockIdx.x * P1P;
    const int t = threadIdx.x;  // 0..191

    if (t < P1P) {
        const int ix = input[p0 + t];
        sidx[t] = ix;
        sqid[t] = ix > QN_ ? ix - QN_ : ix;
    }
    __syncthreads();

    // stage 256 jobs: (tensor, p, 16-elem segment) -> transposed LDS
    for (int rep = 0; rep < 2; ++rep) {
        const int j = (rep == 0) ? t : t + 192;
        if (j < 256) {
            const int tensor = j >> 7;
            const int r = j & 127;
            const int p = r >> 3;
            const int i0 = (r & 7) * 16;
            const int row = tensor ? sqid[p] : sidx[p];
            const void* src = tensor ? q_emb : i_emb;
            float* dst = tensor ? qvT : ivT;
            float x[16];
            ld16<BF>(src, (long long)row * 128 + i0, x);
            #pragma unroll
            for (int k = 0; k < 16; ++k)
                dst[(i0 + k) * 16 + p] = x[k];
        }
    }
    __syncthreads();

    const int g = t >> 6;    // 0=erase cols, 1=add cols, 2=w logits
    const int c = t & 63;

    if (g < 2) {
        const void* W = g ? add_W : erase_W;
        const float2 bb = ld2<BF>(g ? add_b : erase_b, c);
        float acc0[P1P], acc1[P1P];
        #pragma unroll
        for (int p = 0; p < P1P; ++p) { acc0[p] = bb.x; acc1[p] = bb.y; }

        #pragma unroll 8
        for (int i = 0; i < 128; ++i) {
            const float2 wv = ld2<BF>(W, i * 64 + c);     // cols 2c,2c+1 of row i
            const float4* ivr = (const float4*)&ivT[i * 16];
            const float4 x0 = ivr[0], x1 = ivr[1], x2 = ivr[2], x3 = ivr[3];
            const float xx[16] = {x0.x,x0.y,x0.z,x0.w, x1.x,x1.y,x1.z,x1.w,
                                  x2.x,x2.y,x2.z,x2.w, x3.x,x3.y,x3.z,x3.w};
            #pragma unroll
            for (int p = 0; p < P1P; ++p) {
                acc0[p] += xx[p] * wv.x;
                acc1[p] += xx[p] * wv.y;
            }
        }
        if (g == 0) {
            #pragma unroll
            for (int p = 0; p < P1P; ++p) {
                const float o0 = 1.f / (1.f + expf(-acc0[p]));
                const float o1 = 1.f / (1.f + expf(-acc1[p]));
                ((float2*)(e_buf + (size_t)(p0 + p) * V_))[c] = make_float2(o0, o1);
            }
        } else {
            #pragma unroll
            for (int p = 0; p < P1P; ++p)
                ((float2*)(a_buf + (size_t)(p0 + p) * V_))[c] =
                    make_float2(tanhf(acc0[p]), tanhf(acc1[p]));
        }
    } else {
        float acc[P1P];
        #pragma unroll
        for (int p = 0; p < P1P; ++p) acc[p] = 0.f;
        #pragma unroll 8
        for (int i = 0; i < 128; ++i) {
            const float kv = ld<BF>(key_memory, i * C_ + c);
            const float4* qvr = (const float4*)&qvT[i * 16];
            const float4 x0 = qvr[0], x1 = qvr[1], x2 = qvr[2], x3 = qvr[3];
            const float xx[16] = {x0.x,x0.y,x0.z,x0.w, x1.x,x1.y,x1.z,x1.w,
                                  x2.x,x2.y,x2.z,x2.w, x3.x,x3.y,x3.z,x3.w};
            #pragma unroll
            for (int p = 0; p < P1P; ++p) acc[p] += xx[p] * kv;
        }
        #pragma unroll
        for (int p = 0; p < P1P; ++p) {
            float m = acc[p];
            for (int off = 32; off > 0; off >>= 1)
                m = fmaxf(m, __shfl_xor(m, off, 64));
            const float ex = expf(acc[p] - m);
            float ssum = ex;
            for (int off = 32; off > 0; off >>= 1)
                ssum += __shfl_xor(ssum, off, 64);
            w_buf[(size_t)(p0 + p) * C_ + c] = ex / ssum;
        }
    }
}

__global__ __launch_bounds__(192) void dkvmn_phase1(
    const void* q_emb, const void* i_emb, const void* key_memory,
    const void* erase_W, const void* erase_b, const void* add_W, const void* add_b,
    const int* __restrict__ input,
    float* e_buf, float* a_buf, float* w_buf)
{
    __shared__ float ivT[128 * P1P];
    __shared__ float qvT[128 * P1P];
    __shared__ int sidx[P1P], sqid[P1P];
    __shared__ int sflag;
    if (threadIdx.x == 0) sflag = probe_flag(erase_b);
    __syncthreads();
    if (sflag)
        phase1_body<true>(q_emb, i_emb, key_memory, erase_W, erase_b, add_W, add_b,
                          input, e_buf, a_buf, w_buf, ivT, qvT, sidx, sqid);
    else
        phase1_body<false>(q_emb, i_emb, key_memory, erase_W, erase_b, add_W, add_b,
                           input, e_buf, a_buf, w_buf, ivT, qvT, sidx, sqid);
}

// ====== Phase 2: register scan, 1 wave / (b, 4-v group), XCD-affine, 4-deep pipe ======
template<bool BF>
__device__ __forceinline__ void phase2_body(
    const void* q_emb, const void* key_memory, const void* init_value_memory,
    const int* __restrict__ target_id,
    const float* __restrict__ e_buf, const float* __restrict__ a_buf,
    const float* __restrict__ w_buf, float* __restrict__ read_buf)
{
    // XCD-affinity swizzle (r4: FETCH_SIZE 131->16 MB)
    const int bid = blockIdx.x;
    const int x = bid & 7;
    const int j = bid >> 3;          // 0..511
    const int b = x * 16 + (j >> 5); // 16 batches per XCD
    const int vg = j & 31;           // v = vg*4 + k
    const int c = threadIdx.x;       // 0..63
    const int z = opaque_zero();     // NEW vs r4: defeat s_load scalarization

    float mem[4];
    #pragma unroll
    for (int k = 0; k < 4; ++k)
        mem[k] = ld<BF>(init_value_memory, (vg * 4 + k) * C_ + c);

    const float* eb = e_buf + (size_t)b * S_ * V_ + vg * 4 + z;
    const float* ab = a_buf + (size_t)b * S_ * V_ + vg * 4 + z;
    const float* wb = w_buf + (size_t)b * S_ * C_ + c;

    // 4-step software pipeline: 12 vector loads in flight
    float4 pe[4], pa[4];
    float pw[4];
    #pragma unroll
    for (int k = 0; k < 4; ++k) {
        pe[k] = *(const float4*)(eb + (size_t)k * V_);
        pa[k] = *(const float4*)(ab + (size_t)k * V_);
        pw[k] = wb[(size_t)k * C_];
    }
    for (int s0 = 0; s0 < S_; s0 += 4) {
        #pragma unroll
        for (int k = 0; k < 4; ++k) {
            const float4 e4 = pe[k], a4 = pa[k];
            const float wv = pw[k];
            const int sn = s0 + k + 4;
            if (sn < S_) {
                pe[k] = *(const float4*)(eb + (size_t)sn * V_);
                pa[k] = *(const float4*)(ab + (size_t)sn * V_);
                pw[k] = wb[(size_t)sn * C_];
            }
            // mem = mem*(1 - e*w) + a*w == mem + w*(a - mem*e)
            mem[0] = fmaf(wv, fmaf(-mem[0], e4.x, a4.x), mem[0]);
            mem[1] = fmaf(wv, fmaf(-mem[1], e4.y, a4.y), mem[1]);
            mem[2] = fmaf(wv, fmaf(-mem[2], e4.z, a4.z), mem[2]);
            mem[3] = fmaf(wv, fmaf(-mem[3], e4.w, a4.w), mem[3]);
        }
    }

    // wt = softmax_c(qv @ key_memory), computed redundantly per block
    const long long qrow = (long long)target_id[b] * K_;
    float logit = 0.f;
    #pragma unroll 8
    for (int i = 0; i < K_; ++i)
        logit += ld<BF>(q_emb, qrow + i) * ld<BF>(key_memory, i * C_ + c);
    float m = logit;
    for (int off = 32; off > 0; off >>= 1)
        m = fmaxf(m, __shfl_xor(m, off, 64));
    const float ex = expf(logit - m);
    float ssum = ex;
    for (int off = 32; off > 0; off >>= 1)
        ssum += __shfl_xor(ssum, off, 64);
    const float wt = ex / ssum;

    #pragma unroll
    for (int k = 0; k < 4; ++k) {
        float r = mem[k] * wt;
        for (int off = 32; off > 0; off >>= 1)
            r += __shfl_xor(r, off, 64);
        if (c == 0) read_buf[b * V_ + vg * 4 + k] = r;
    }
}

__global__ __launch_bounds__(64) void dkvmn_phase2(
    const void* q_emb, const void* key_memory, const void* init_value_memory,
    const void* erase_b,
    const int* __restrict__ target_id,
    const float* e_buf, const float* a_buf, const float* w_buf,
    float* read_buf)
{
    __shared__ int sflag;
    if (threadIdx.x == 0) sflag = probe_flag(erase_b);
    __syncthreads();
    if (sflag)
        phase2_body<true>(q_emb, key_memory, init_value_memory, target_id,
                          e_buf, a_buf, w_buf, read_buf);
    else
        phase2_body<false>(q_emb, key_memory, init_value_memory, target_id,
                           e_buf, a_buf, w_buf, read_buf);
}

// ================= Phase 3: summ mat-vec + scalar out =================
template<bool BF>
__device__ __forceinline__ void phase3_body(
    const void* q_emb, const void* summ_W, const void* summ_b,
    const void* out_W, const void* out_b,
    const int* __restrict__ target_id, const float* __restrict__ read_buf,
    void* outp, float* summl)
{
    const int b = blockIdx.x;
    const int t = threadIdx.x;  // 0..127
    const long long qrow = (long long)target_id[b] * K_;

    float acc = ld<BF>(summ_b, t);
    #pragma unroll 8
    for (int i = 0; i < 128; ++i)
        acc += read_buf[b * V_ + i] * ld<BF>(summ_W, i * SUM_ + t);
    #pragma unroll 8
    for (int i = 0; i < 128; ++i)
        acc += ld<BF>(q_emb, qrow + i) * ld<BF>(summ_W, (128 + i) * SUM_ + t);
    summl[t] = tanhf(acc);
    __syncthreads();

    if (t < 64) {
        float pacc = summl[t] * ld<BF>(out_W, t) + summl[t + 64] * ld<BF>(out_W, t + 64);
        for (int off = 32; off > 0; off >>= 1)
            pacc += __shfl_xor(pacc, off, 64);
        if (t == 0) {
            const float res = pacc + ld<BF>(out_b, 0);
            if (BF) ((__hip_bfloat16*)outp)[b] = __float2bfloat16(res);
            else    ((float*)outp)[b] = res;
        }
    }
}

__global__ __launch_bounds__(128) void dkvmn_phase3(
    const void* q_emb, const void* summ_W, const void* summ_b,
    const void* out_W, const void* out_b, const void* erase_b,
    const int* __restrict__ target_id, const float* read_buf,
    void* outp)
{
    __shared__ float summl[SUM_];
    __shared__ int sflag;
    if (threadIdx.x == 0) sflag = probe_flag(erase_b);
    __syncthreads();
    if (sflag)
        phase3_body<true>(q_emb, summ_W, summ_b, out_W, out_b, target_id,
                          read_buf, outp, summl);
    else
        phase3_body<false>(q_emb, summ_W, summ_b, out_W, out_b, target_id,
                           read_buf, outp, summl);
}

extern "C" void kernel_launch(void* const* d_in, const int* in_sizes, int n_in,
                              void* d_out, int out_size, void* d_ws, size_t ws_size,
                              hipStream_t stream) {
    const void* q_emb             = d_in[0];
    const void* i_emb             = d_in[1];
    const void* key_memory        = d_in[2];
    const void* init_value_memory = d_in[3];
    const void* erase_W           = d_in[4];
    const void* erase_b           = d_in[5];
    const void* add_W             = d_in[6];
    const void* add_b             = d_in[7];
    const void* summ_W            = d_in[8];
    const void* summ_b            = d_in[9];
    const void* out_W             = d_in[10];
    const void* out_b             = d_in[11];
    const int* input     = (const int*)d_in[12];
    const int* target_id = (const int*)d_in[13];

    // ws: [e B*S*V f32][a B*S*V f32][w B*S*C f32][read B*V f32]
    float* e_buf    = (float*)d_ws;
    float* a_buf    = e_buf + (size_t)B_ * S_ * V_;
    float* w_buf    = a_buf + (size_t)B_ * S_ * V_;
    float* read_buf = w_buf + (size_t)B_ * S_ * C_;

    dkvmn_phase1<<<(B_ * S_) / P1P, 192, 0, stream>>>(
        q_emb, i_emb, key_memory, erase_W, erase_b, add_W, add_b,
        input, e_buf, a_buf, w_buf);
    dkvmn_phase2<<<B_ * 32, 64, 0, stream>>>(
        q_emb, key_memory, init_value_memory, erase_b, target_id,
        e_buf, a_buf, w_buf, read_buf);
    dkvmn_phase3<<<B_, 128, 0, stream>>>(
        q_emb, summ_W, summ_b, out_W, out_b, erase_b, target_id, read_buf, d_out);
}

// Round 7
// 185.000 us; speedup vs baseline: 1.2585x; 1.2471x over previous
//
#include <hip/hip_runtime.h>
#include <hip/hip_bf16.h>

#define B_ 128
#define S_ 200
#define QN_ 20000
#define V_ 128
#define K_ 128
#define C_ 64
#define SUM_ 128
#define P1P 16   // positions per phase1 block

// ---- dtype-generic loads (BF=true: bf16, BF=false: fp32) ----
template<bool BF>
__device__ __forceinline__ float ld(const void* p, long long i) {
    if (BF) return __bfloat162float(((const __hip_bfloat16*)p)[i]);
    return ((const float*)p)[i];
}
template<bool BF>
__device__ __forceinline__ float2 ld2(const void* p, long long i) {  // elems 2i, 2i+1
    if (BF) {
        __hip_bfloat162 v = ((const __hip_bfloat162*)p)[i];
        return make_float2(__bfloat162float(v.x), __bfloat162float(v.y));
    }
    return ((const float2*)p)[i];
}
// 8 consecutive elements at elem offset off (off multiple of 8)
template<bool BF>
__device__ __forceinline__ void ld8(const void* p, long long off, float* out) {
    if (BF) {
        const uint4 u = *(const uint4*)((const unsigned short*)p + off);
        const unsigned uu[4] = {u.x, u.y, u.z, u.w};
        #pragma unroll
        for (int k = 0; k < 4; ++k) {
            out[2 * k]     = __uint_as_float(uu[k] << 16);
            out[2 * k + 1] = __uint_as_float(uu[k] & 0xffff0000u);
        }
    } else {
        const float4* q = (const float4*)((const float*)p + off);
        const float4 f0 = q[0], f1 = q[1];
        out[0]=f0.x; out[1]=f0.y; out[2]=f0.z; out[3]=f0.w;
        out[4]=f1.x; out[5]=f1.y; out[6]=f1.z; out[7]=f1.w;
    }
}
// 16 consecutive elements starting at elem offset off (off must be mult. of 16)
template<bool BF>
__device__ __forceinline__ void ld16(const void* p, long long off, float* out) {
    if (BF) {
        const uint4* q = (const uint4*)((const unsigned short*)p + off);
        uint4 u0 = q[0], u1 = q[1];
        unsigned uu[8] = {u0.x, u0.y, u0.z, u0.w, u1.x, u1.y, u1.z, u1.w};
        #pragma unroll
        for (int k = 0; k < 8; ++k) {
            out[2 * k]     = __uint_as_float(uu[k] << 16);
            out[2 * k + 1] = __uint_as_float(uu[k] & 0xffff0000u);
        }
    } else {
        const float4* q = (const float4*)((const float*)p + off);
        float4 f0 = q[0], f1 = q[1], f2 = q[2], f3 = q[3];
        out[0]=f0.x; out[1]=f0.y; out[2]=f0.z; out[3]=f0.w;
        out[4]=f1.x; out[5]=f1.y; out[6]=f1.z; out[7]=f1.w;
        out[8]=f2.x; out[9]=f2.y; out[10]=f2.z; out[11]=f2.w;
        out[12]=f3.x; out[13]=f3.y; out[14]=f3.z; out[15]=f3.w;
    }
}

// ---- dtype probe, computed per-block (no separate dispatch) ----
__device__ __forceinline__ int probe_flag(const void* erase_b) {
    const unsigned* w = (const unsigned*)erase_b;
    int bad = 0;
    #pragma unroll 8
    for (int i = 0; i < 64; ++i) {
        unsigned lo = w[i] & 0xffffu;
        float f = __uint_as_float(lo << 16);
        if (!(fabsf(f) <= 0.5f)) bad++;  // NaN also fails
    }
    return (bad <= 8) ? 1 : 0;  // 1 = bf16
}

// ================= Phase 1: batched mat-vecs, P=16 positions/block =================
// (unchanged from round 6 — isolate the phase2 experiment)
template<bool BF>
__device__ __forceinline__ void phase1_body(
    const void* q_emb, const void* i_emb, const void* key_memory,
    const void* erase_W, const void* erase_b, const void* add_W, const void* add_b,
    const int* __restrict__ input,
    float* __restrict__ e_buf, float* __restrict__ a_buf, float* __restrict__ w_buf,
    float* ivT, float* qvT, int* sidx, int* sqid)
{
    const int p0 = blockIdx.x * P1P;
    const int t = threadIdx.x;  // 0..191

    if (t < P1P) {
        const int ix = input[p0 + t];
        sidx[t] = ix;
        sqid[t] = ix > QN_ ? ix - QN_ : ix;
    }
    __syncthreads();

    for (int rep = 0; rep < 2; ++rep) {
        const int j = (rep == 0) ? t : t + 192;
        if (j < 256) {
            const int tensor = j >> 7;
            const int r = j & 127;
            const int p = r >> 3;
            const int i0 = (r & 7) * 16;
            const int row = tensor ? sqid[p] : sidx[p];
            const void* src = tensor ? q_emb : i_emb;
            float* dst = tensor ? qvT : ivT;
            float x[16];
            ld16<BF>(src, (long long)row * 128 + i0, x);
            #pragma unroll
            for (int k = 0; k < 16; ++k)
                dst[(i0 + k) * 16 + p] = x[k];
        }
    }
    __syncthreads();

    const int g = t >> 6;    // 0=erase cols, 1=add cols, 2=w logits
    const int c = t & 63;

    if (g < 2) {
        const void* W = g ? add_W : erase_W;
        const float2 bb = ld2<BF>(g ? add_b : erase_b, c);
        float acc0[P1P], acc1[P1P];
        #pragma unroll
        for (int p = 0; p < P1P; ++p) { acc0[p] = bb.x; acc1[p] = bb.y; }

        #pragma unroll 8
        for (int i = 0; i < 128; ++i) {
            const float2 wv = ld2<BF>(W, i * 64 + c);
            const float4* ivr = (const float4*)&ivT[i * 16];
            const float4 x0 = ivr[0], x1 = ivr[1], x2 = ivr[2], x3 = ivr[3];
            const float xx[16] = {x0.x,x0.y,x0.z,x0.w, x1.x,x1.y,x1.z,x1.w,
                                  x2.x,x2.y,x2.z,x2.w, x3.x,x3.y,x3.z,x3.w};
            #pragma unroll
            for (int p = 0; p < P1P; ++p) {
                acc0[p] += xx[p] * wv.x;
                acc1[p] += xx[p] * wv.y;
            }
        }
        if (g == 0) {
            #pragma unroll
            for (int p = 0; p < P1P; ++p) {
                const float o0 = 1.f / (1.f + expf(-acc0[p]));
                const float o1 = 1.f / (1.f + expf(-acc1[p]));
                ((float2*)(e_buf + (size_t)(p0 + p) * V_))[c] = make_float2(o0, o1);
            }
        } else {
            #pragma unroll
            for (int p = 0; p < P1P; ++p)
                ((float2*)(a_buf + (size_t)(p0 + p) * V_))[c] =
                    make_float2(tanhf(acc0[p]), tanhf(acc1[p]));
        }
    } else {
        float acc[P1P];
        #pragma unroll
        for (int p = 0; p < P1P; ++p) acc[p] = 0.f;
        #pragma unroll 8
        for (int i = 0; i < 128; ++i) {
            const float kv = ld<BF>(key_memory, i * C_ + c);
            const float4* qvr = (const float4*)&qvT[i * 16];
            const float4 x0 = qvr[0], x1 = qvr[1], x2 = qvr[2], x3 = qvr[3];
            const float xx[16] = {x0.x,x0.y,x0.z,x0.w, x1.x,x1.y,x1.z,x1.w,
                                  x2.x,x2.y,x2.z,x2.w, x3.x,x3.y,x3.z,x3.w};
            #pragma unroll
            for (int p = 0; p < P1P; ++p) acc[p] += xx[p] * kv;
        }
        #pragma unroll
        for (int p = 0; p < P1P; ++p) {
            float m = acc[p];
            for (int off = 32; off > 0; off >>= 1)
                m = fmaxf(m, __shfl_xor(m, off, 64));
            const float ex = expf(acc[p] - m);
            float ssum = ex;
            for (int off = 32; off > 0; off >>= 1)
                ssum += __shfl_xor(ssum, off, 64);
            w_buf[(size_t)(p0 + p) * C_ + c] = ex / ssum;
        }
    }
}

__global__ __launch_bounds__(192) void dkvmn_phase1(
    const void* q_emb, const void* i_emb, const void* key_memory,
    const void* erase_W, const void* erase_b, const void* add_W, const void* add_b,
    const int* __restrict__ input,
    float* e_buf, float* a_buf, float* w_buf)
{
    __shared__ float ivT[128 * P1P];
    __shared__ float qvT[128 * P1P];
    __shared__ int sidx[P1P], sqid[P1P];
    __shared__ int sflag;
    if (threadIdx.x == 0) sflag = probe_flag(erase_b);
    __syncthreads();
    if (sflag)
        phase1_body<true>(q_emb, i_emb, key_memory, erase_W, erase_b, add_W, add_b,
                          input, e_buf, a_buf, w_buf, ivT, qvT, sidx, sqid);
    else
        phase1_body<false>(q_emb, i_emb, key_memory, erase_W, erase_b, add_W, add_b,
                           input, e_buf, a_buf, w_buf, ivT, qvT, sidx, sqid);
}

// ====== Phase 2: one block (256 thr) per batch; thread owns 4v x 8c state tile ======
__device__ __forceinline__ void scan_step(float mem[4][8], float4 e4, float4 a4,
                                          float4 w0, float4 w1) {
    const float ev[4] = {e4.x, e4.y, e4.z, e4.w};
    const float av[4] = {a4.x, a4.y, a4.z, a4.w};
    const float wv[8] = {w0.x, w0.y, w0.z, w0.w, w1.x, w1.y, w1.z, w1.w};
    #pragma unroll
    for (int i = 0; i < 4; ++i)
        #pragma unroll
        for (int j = 0; j < 8; ++j)
            mem[i][j] = fmaf(wv[j], fmaf(-mem[i][j], ev[i], av[i]), mem[i][j]);
}

template<bool BF>
__device__ __forceinline__ void phase2_body(
    const void* q_emb, const void* key_memory, const void* init_value_memory,
    const int* __restrict__ target_id,
    const float* __restrict__ e_buf, const float* __restrict__ a_buf,
    const float* __restrict__ w_buf, float* __restrict__ read_buf,
    float* wtl)
{
    const int b = blockIdx.x;
    const int t = threadIdx.x;     // 0..255
    const int vg = t >> 3;         // 0..31
    const int cg = t & 7;          // 0..7
    const int v0 = vg * 4, c0 = cg * 8;

    // state tile: mem[i][j] = M[v0+i][c0+j]
    float mem[4][8];
    #pragma unroll
    for (int i = 0; i < 4; ++i)
        ld8<BF>(init_value_memory, (long long)(v0 + i) * C_ + c0, mem[i]);

    const float* eb = e_buf + (size_t)b * S_ * V_ + v0;
    const float* ab = a_buf + (size_t)b * S_ * V_ + v0;
    const float* wb = w_buf + (size_t)b * S_ * C_ + c0;

    // depth-5 branch-free pipeline (200 = 5*40)
    float4 pe[5], pa[5], pw0[5], pw1[5];
    #pragma unroll
    for (int k = 0; k < 5; ++k) {
        pe[k]  = *(const float4*)(eb + (size_t)k * V_);
        pa[k]  = *(const float4*)(ab + (size_t)k * V_);
        pw0[k] = *(const float4*)(wb + (size_t)k * C_);
        pw1[k] = *(const float4*)(wb + (size_t)k * C_ + 4);
    }
    for (int s0 = 0; s0 < 195; s0 += 5) {   // s0 = 0,5,...,190
        #pragma unroll
        for (int k = 0; k < 5; ++k) {
            const float4 E = pe[k], A = pa[k], W0 = pw0[k], W1 = pw1[k];
            const size_t sn = (size_t)(s0 + k + 5);      // <= 199, always valid
            pe[k]  = *(const float4*)(eb + sn * V_);
            pa[k]  = *(const float4*)(ab + sn * V_);
            pw0[k] = *(const float4*)(wb + sn * C_);
            pw1[k] = *(const float4*)(wb + sn * C_ + 4);
            scan_step(mem, E, A, W0, W1);
        }
    }
    #pragma unroll
    for (int k = 0; k < 5; ++k)                          // steps 195..199
        scan_step(mem, pe[k], pa[k], pw0[k], pw1[k]);

    // wt = softmax_c(q_emb[target[b]] @ key_memory), wave 0 -> LDS
    if (t < 64) {
        const long long qrow = (long long)target_id[b] * K_;
        float logit = 0.f;
        #pragma unroll 8
        for (int i = 0; i < K_; ++i)
            logit += ld<BF>(q_emb, qrow + i) * ld<BF>(key_memory, i * C_ + t);
        float m = logit;
        for (int off = 32; off > 0; off >>= 1)
            m = fmaxf(m, __shfl_xor(m, off, 64));
        const float ex = expf(logit - m);
        float ssum = ex;
        for (int off = 32; off > 0; off >>= 1)
            ssum += __shfl_xor(ssum, off, 64);
        wtl[t] = ex / ssum;
    }
    __syncthreads();

    float wt[8];
    *(float4*)&wt[0] = *(const float4*)&wtl[c0];
    *(float4*)&wt[4] = *(const float4*)&wtl[c0 + 4];

    float red[4];
    #pragma unroll
    for (int i = 0; i < 4; ++i) {
        float acc = 0.f;
        #pragma unroll
        for (int j = 0; j < 8; ++j) acc += mem[i][j] * wt[j];
        red[i] = acc;
    }
    // reduce over the 8 c-groups (lane bits 0..2)
    #pragma unroll
    for (int off = 1; off < 8; off <<= 1) {
        #pragma unroll
        for (int i = 0; i < 4; ++i)
            red[i] += __shfl_xor(red[i], off, 64);
    }
    if (cg == 0)
        *(float4*)(read_buf + (size_t)b * V_ + v0) =
            make_float4(red[0], red[1], red[2], red[3]);
}

__global__ __launch_bounds__(256) void dkvmn_phase2(
    const void* q_emb, const void* key_memory, const void* init_value_memory,
    const void* erase_b,
    const int* __restrict__ target_id,
    const float* e_buf, const float* a_buf, const float* w_buf,
    float* read_buf)
{
    __shared__ float wtl[C_];
    __shared__ int sflag;
    if (threadIdx.x == 0) sflag = probe_flag(erase_b);
    __syncthreads();
    if (sflag)
        phase2_body<true>(q_emb, key_memory, init_value_memory, target_id,
                          e_buf, a_buf, w_buf, read_buf, wtl);
    else
        phase2_body<false>(q_emb, key_memory, init_value_memory, target_id,
                           e_buf, a_buf, w_buf, read_buf, wtl);
}

// ================= Phase 3: summ mat-vec + scalar out =================
template<bool BF>
__device__ __forceinline__ void phase3_body(
    const void* q_emb, const void* summ_W, const void* summ_b,
    const void* out_W, const void* out_b,
    const int* __restrict__ target_id, const float* __restrict__ read_buf,
    void* outp, float* summl)
{
    const int b = blockIdx.x;
    const int t = threadIdx.x;  // 0..127
    const long long qrow = (long long)target_id[b] * K_;

    float acc = ld<BF>(summ_b, t);
    #pragma unroll 8
    for (int i = 0; i < 128; ++i)
        acc += read_buf[b * V_ + i] * ld<BF>(summ_W, i * SUM_ + t);
    #pragma unroll 8
    for (int i = 0; i < 128; ++i)
        acc += ld<BF>(q_emb, qrow + i) * ld<BF>(summ_W, (128 + i) * SUM_ + t);
    summl[t] = tanhf(acc);
    __syncthreads();

    if (t < 64) {
        float pacc = summl[t] * ld<BF>(out_W, t) + summl[t + 64] * ld<BF>(out_W, t + 64);
        for (int off = 32; off > 0; off >>= 1)
            pacc += __shfl_xor(pacc, off, 64);
        if (t == 0) {
            const float res = pacc + ld<BF>(out_b, 0);
            if (BF) ((__hip_bfloat16*)outp)[b] = __float2bfloat16(res);
            else    ((float*)outp)[b] = res;
        }
    }
}

__global__ __launch_bounds__(128) void dkvmn_phase3(
    const void* q_emb, const void* summ_W, const void* summ_b,
    const void* out_W, const void* out_b, const void* erase_b,
    const int* __restrict__ target_id, const float* read_buf,
    void* outp)
{
    __shared__ float summl[SUM_];
    __shared__ int sflag;
    if (threadIdx.x == 0) sflag = probe_flag(erase_b);
    __syncthreads();
    if (sflag)
        phase3_body<true>(q_emb, summ_W, summ_b, out_W, out_b, target_id,
                          read_buf, outp, summl);
    else
        phase3_body<false>(q_emb, summ_W, summ_b, out_W, out_b, target_id,
                           read_buf, outp, summl);
}

extern "C" void kernel_launch(void* const* d_in, const int* in_sizes, int n_in,
                              void* d_out, int out_size, void* d_ws, size_t ws_size,
                              hipStream_t stream) {
    const void* q_emb             = d_in[0];
    const void* i_emb             = d_in[1];
    const void* key_memory        = d_in[2];
    const void* init_value_memory = d_in[3];
    const void* erase_W           = d_in[4];
    const void* erase_b           = d_in[5];
    const void* add_W             = d_in[6];
    const void* add_b             = d_in[7];
    const void* summ_W            = d_in[8];
    const void* summ_b            = d_in[9];
    const void* out_W             = d_in[10];
    const void* out_b             = d_in[11];
    const int* input     = (const int*)d_in[12];
    const int* target_id = (const int*)d_in[13];

    // ws: [e B*S*V f32][a B*S*V f32][w B*S*C f32][read B*V f32]
    float* e_buf    = (float*)d_ws;
    float* a_buf    = e_buf + (size_t)B_ * S_ * V_;
    float* w_buf    = a_buf + (size_t)B_ * S_ * V_;
    float* read_buf = w_buf + (size_t)B_ * S_ * C_;

    dkvmn_phase1<<<(B_ * S_) / P1P, 192, 0, stream>>>(
        q_emb, i_emb, key_memory, erase_W, erase_b, add_W, add_b,
        input, e_buf, a_buf, w_buf);
    dkvmn_phase2<<<B_, 256, 0, stream>>>(
        q_emb, key_memory, init_value_memory, erase_b, target_id,
        e_buf, a_buf, w_buf, read_buf);
    dkvmn_phase3<<<B_, 128, 0, stream>>>(
        q_emb, summ_W, summ_b, out_W, out_b, erase_b, target_id, read_buf, d_out);
}

// Round 8
// 173.374 us; speedup vs baseline: 1.3429x; 1.0671x over previous
//
#include <hip/hip_runtime.h>
#include <hip/hip_bf16.h>

#define B_ 128
#define S_ 200
#define QN_ 20000
#define V_ 128
#define K_ 128
#define C_ 64
#define SUM_ 128
#define P1P 16   // positions per legacy phase1 block

using short8 = __attribute__((ext_vector_type(8))) short;
using f32x4  = __attribute__((ext_vector_type(4))) float;

// ---- dtype-generic loads (BF=true: bf16, BF=false: fp32) ----
template<bool BF>
__device__ __forceinline__ float ld(const void* p, long long i) {
    if (BF) return __bfloat162float(((const __hip_bfloat16*)p)[i]);
    return ((const float*)p)[i];
}
template<bool BF>
__device__ __forceinline__ float2 ld2(const void* p, long long i) {  // elems 2i, 2i+1
    if (BF) {
        __hip_bfloat162 v = ((const __hip_bfloat162*)p)[i];
        return make_float2(__bfloat162float(v.x), __bfloat162float(v.y));
    }
    return ((const float2*)p)[i];
}
template<bool BF>
__device__ __forceinline__ void ld16(const void* p, long long off, float* out) {
    if (BF) {
        const uint4* q = (const uint4*)((const unsigned short*)p + off);
        uint4 u0 = q[0], u1 = q[1];
        unsigned uu[8] = {u0.x, u0.y, u0.z, u0.w, u1.x, u1.y, u1.z, u1.w};
        #pragma unroll
        for (int k = 0; k < 8; ++k) {
            out[2 * k]     = __uint_as_float(uu[k] << 16);
            out[2 * k + 1] = __uint_as_float(uu[k] & 0xffff0000u);
        }
    } else {
        const float4* q = (const float4*)((const float*)p + off);
        float4 f0 = q[0], f1 = q[1], f2 = q[2], f3 = q[3];
        out[0]=f0.x; out[1]=f0.y; out[2]=f0.z; out[3]=f0.w;
        out[4]=f1.x; out[5]=f1.y; out[6]=f1.z; out[7]=f1.w;
        out[8]=f2.x; out[9]=f2.y; out[10]=f2.z; out[11]=f2.w;
        out[12]=f3.x; out[13]=f3.y; out[14]=f3.z; out[15]=f3.w;
    }
}

// ---- dtype probe, one load/lane + ballot (wave-uniform result, ~300 cyc) ----
__device__ __forceinline__ int probe_flag_wave(const void* erase_b) {
    const unsigned* w = (const unsigned*)erase_b;
    const int lane = threadIdx.x & 63;
    const unsigned lo = w[lane] & 0xffffu;
    const float f = __uint_as_float(lo << 16);
    const unsigned long long bal = __ballot(!(fabsf(f) <= 0.5f));
    return (__popcll(bal) <= 8) ? 1 : 0;  // 1 = bf16
}

// ============ Phase 1 (fp32 fallback, legacy path — no-ops when data is bf16) ==========
__device__ __forceinline__ void phase1_body_f32(
    const void* q_emb, const void* i_emb, const void* key_memory,
    const void* erase_W, const void* erase_b, const void* add_W, const void* add_b,
    const int* __restrict__ input,
    float* __restrict__ e_buf, float* __restrict__ a_buf, float* __restrict__ w_buf,
    float* ivT, float* qvT, int* sidx, int* sqid)
{
    const bool BF = false;
    const int p0 = blockIdx.x * P1P;
    const int t = threadIdx.x;  // 0..191

    if (t < P1P) {
        const int ix = input[p0 + t];
        sidx[t] = ix;
        sqid[t] = ix > QN_ ? ix - QN_ : ix;
    }
    __syncthreads();

    for (int rep = 0; rep < 2; ++rep) {
        const int j = (rep == 0) ? t : t + 192;
        if (j < 256) {
            const int tensor = j >> 7;
            const int r = j & 127;
            const int p = r >> 3;
            const int i0 = (r & 7) * 16;
            const int row = tensor ? sqid[p] : sidx[p];
            const void* src = tensor ? q_emb : i_emb;
            float* dst = tensor ? qvT : ivT;
            float x[16];
            ld16<BF>(src, (long long)row * 128 + i0, x);
            #pragma unroll
            for (int k = 0; k < 16; ++k)
                dst[(i0 + k) * 16 + p] = x[k];
        }
    }
    __syncthreads();

    const int g = t >> 6;
    const int c = t & 63;

    if (g < 2) {
        const void* W = g ? add_W : erase_W;
        const float2 bb = ld2<BF>(g ? add_b : erase_b, c);
        float acc0[P1P], acc1[P1P];
        #pragma unroll
        for (int p = 0; p < P1P; ++p) { acc0[p] = bb.x; acc1[p] = bb.y; }
        #pragma unroll 8
        for (int i = 0; i < 128; ++i) {
            const float2 wv = ld2<BF>(W, i * 64 + c);
            const float4* ivr = (const float4*)&ivT[i * 16];
            const float4 x0 = ivr[0], x1 = ivr[1], x2 = ivr[2], x3 = ivr[3];
            const float xx[16] = {x0.x,x0.y,x0.z,x0.w, x1.x,x1.y,x1.z,x1.w,
                                  x2.x,x2.y,x2.z,x2.w, x3.x,x3.y,x3.z,x3.w};
            #pragma unroll
            for (int p = 0; p < P1P; ++p) {
                acc0[p] += xx[p] * wv.x;
                acc1[p] += xx[p] * wv.y;
            }
        }
        if (g == 0) {
            #pragma unroll
            for (int p = 0; p < P1P; ++p) {
                const float o0 = 1.f / (1.f + expf(-acc0[p]));
                const float o1 = 1.f / (1.f + expf(-acc1[p]));
                ((float2*)(e_buf + (size_t)(p0 + p) * V_))[c] = make_float2(o0, o1);
            }
        } else {
            #pragma unroll
            for (int p = 0; p < P1P; ++p)
                ((float2*)(a_buf + (size_t)(p0 + p) * V_))[c] =
                    make_float2(tanhf(acc0[p]), tanhf(acc1[p]));
        }
    } else {
        float acc[P1P];
        #pragma unroll
        for (int p = 0; p < P1P; ++p) acc[p] = 0.f;
        #pragma unroll 8
        for (int i = 0; i < 128; ++i) {
            const float kv = ld<BF>(key_memory, i * C_ + c);
            const float4* qvr = (const float4*)&qvT[i * 16];
            const float4 x0 = qvr[0], x1 = qvr[1], x2 = qvr[2], x3 = qvr[3];
            const float xx[16] = {x0.x,x0.y,x0.z,x0.w, x1.x,x1.y,x1.z,x1.w,
                                  x2.x,x2.y,x2.z,x2.w, x3.x,x3.y,x3.z,x3.w};
            #pragma unroll
            for (int p = 0; p < P1P; ++p) acc[p] += xx[p] * kv;
        }
        #pragma unroll
        for (int p = 0; p < P1P; ++p) {
            float m = acc[p];
            for (int off = 32; off > 0; off >>= 1)
                m = fmaxf(m, __shfl_xor(m, off, 64));
            const float ex = expf(acc[p] - m);
            float ssum = ex;
            for (int off = 32; off > 0; off >>= 1)
                ssum += __shfl_xor(ssum, off, 64);
            w_buf[(size_t)(p0 + p) * C_ + c] = ex / ssum;
        }
    }
}

__global__ __launch_bounds__(192) void dkvmn_phase1_f32(
    const void* q_emb, const void* i_emb, const void* key_memory,
    const void* erase_W, const void* erase_b, const void* add_W, const void* add_b,
    const int* __restrict__ input,
    float* e_buf, float* a_buf, float* w_buf)
{
    __shared__ float ivT[128 * P1P];
    __shared__ float qvT[128 * P1P];
    __shared__ int sidx[P1P], sqid[P1P];
    if (probe_flag_wave(erase_b)) return;   // bf16 -> handled by MFMA kernel
    phase1_body_f32(q_emb, i_emb, key_memory, erase_W, erase_b, add_W, add_b,
                    input, e_buf, a_buf, w_buf, ivT, qvT, sidx, sqid);
}

// ============ Phase 1 (bf16 MFMA path): 64 positions/block, 4 waves ==========
// GEMM: [64 x 128] @ { erase_W, add_W (128x128), key (128x64) } -> N=320 cols.
// mfma_f32_16x16x32_bf16 layouts: A[m=l&15][k=(l>>4)*8+j], B[k][n=l&15],
// D: row=(l>>4)*4+reg, col=l&15  (m89-verified).
__global__ __launch_bounds__(256) void dkvmn_phase1_mfma(
    const void* q_emb, const void* i_emb, const void* key_memory,
    const void* erase_W, const void* erase_b, const void* add_W, const void* add_b,
    const int* __restrict__ input,
    float* __restrict__ e_buf, float* __restrict__ a_buf, float* __restrict__ w_buf)
{
    __shared__ unsigned short ivA[64 * 136];  // padded rows: 2-way banks (free)
    __shared__ unsigned short qvA[64 * 136];
    __shared__ float wlog[64 * 68];
    __shared__ int sidx[64], sqid[64];

    if (!probe_flag_wave(erase_b)) return;    // fp32 -> legacy kernel

    const int p0 = blockIdx.x * 64;
    const int t = threadIdx.x;      // 0..255
    const int wv = t >> 6;          // wave 0..3
    const int lane = t & 63;
    const int lrow = lane & 15;     // m (A) / n (B) / col (D)
    const int lk8 = (lane >> 4) * 8;

    if (t < 64) {
        const int ix = input[p0 + t];
        sidx[t] = ix;
        sqid[t] = ix > QN_ ? ix - QN_ : ix;
    }
    __syncthreads();

    // stage A: 2 tensors x 64 rows x 16 segs of 16B
    #pragma unroll
    for (int r = 0; r < 8; ++r) {
        const int j = t + 256 * r;          // 0..2047
        const int tensor = j >> 10;
        const int row = (j >> 4) & 63;
        const int seg = j & 15;
        const unsigned short* src = (const unsigned short*)(tensor ? q_emb : i_emb);
        const int gr = tensor ? sqid[row] : sidx[row];
        const uint4 v = *(const uint4*)(src + (long long)gr * 128 + seg * 8);
        unsigned short* dst = tensor ? qvA : ivA;
        *(uint4*)(dst + row * 136 + seg * 8) = v;
    }

    // B fragments from global (weights L2-resident, reused by all 400 blocks)
    short8 bfr[5][4];
    int nco[5];
    float biasq[4];
    #pragma unroll
    for (int q = 0; q < 5; ++q) {
        const int nt = wv + 4 * q;          // 0..19
        const unsigned short* Wsrc;
        int ncol, ldn;
        if (q < 2)      { Wsrc = (const unsigned short*)erase_W; ncol = nt * 16 + lrow; ldn = 128; }
        else if (q < 4) { Wsrc = (const unsigned short*)add_W;   ncol = (nt - 8) * 16 + lrow; ldn = 128; }
        else            { Wsrc = (const unsigned short*)key_memory; ncol = (nt - 16) * 16 + lrow; ldn = 64; }
        nco[q] = ncol;
        if (q < 2)      biasq[q] = ld<true>(erase_b, ncol);
        else if (q < 4) biasq[q] = ld<true>(add_b, ncol);
        #pragma unroll
        for (int ks = 0; ks < 4; ++ks) {
            short8 bb;
            #pragma unroll
            for (int jj = 0; jj < 8; ++jj)
                bb[jj] = (short)Wsrc[(ks * 32 + lk8 + jj) * ldn + ncol];
            bfr[q][ks] = bb;
        }
    }
    __syncthreads();

    // IV-based tiles: erase (q=0,1) and add (q=2,3)
    for (int mt = 0; mt < 4; ++mt) {
        short8 afr[4];
        const unsigned short* ar = ivA + (mt * 16 + lrow) * 136 + lk8;
        #pragma unroll
        for (int ks = 0; ks < 4; ++ks)
            afr[ks] = *(const short8*)(ar + ks * 32);
        #pragma unroll
        for (int q = 0; q < 4; ++q) {
            f32x4 acc = {0.f, 0.f, 0.f, 0.f};
            #pragma unroll
            for (int ks = 0; ks < 4; ++ks)
                acc = __builtin_amdgcn_mfma_f32_16x16x32_bf16(afr[ks], bfr[q][ks], acc, 0, 0, 0);
            float* dst = (q < 2) ? e_buf : a_buf;
            const int ncol = nco[q];
            const float bb = biasq[q];
            #pragma unroll
            for (int r = 0; r < 4; ++r) {
                const int prow = p0 + mt * 16 + (lane >> 4) * 4 + r;
                const float y = acc[r] + bb;
                dst[(size_t)prow * V_ + ncol] =
                    (q < 2) ? 1.f / (1.f + expf(-y)) : tanhf(y);
            }
        }
    }
    // QV-based key tile (q=4): logits -> LDS
    for (int mt = 0; mt < 4; ++mt) {
        short8 afr[4];
        const unsigned short* ar = qvA + (mt * 16 + lrow) * 136 + lk8;
        #pragma unroll
        for (int ks = 0; ks < 4; ++ks)
            afr[ks] = *(const short8*)(ar + ks * 32);
        f32x4 acc = {0.f, 0.f, 0.f, 0.f};
        #pragma unroll
        for (int ks = 0; ks < 4; ++ks)
            acc = __builtin_amdgcn_mfma_f32_16x16x32_bf16(afr[ks], bfr[4][ks], acc, 0, 0, 0);
        #pragma unroll
        for (int r = 0; r < 4; ++r)
            wlog[(mt * 16 + (lane >> 4) * 4 + r) * 68 + nco[4]] = acc[r];
    }
    __syncthreads();

    // softmax over 64 logits/row: thread t -> row t>>2, 16-col segment t&3
    {
        const int row = t >> 2;
        const int cs = t & 3;
        const float* wr = &wlog[row * 68 + cs * 16];
        float v[16];
        #pragma unroll
        for (int ii = 0; ii < 4; ++ii)
            *(float4*)&v[ii * 4] = *(const float4*)&wr[ii * 4];
        float m = v[0];
        #pragma unroll
        for (int ii = 1; ii < 16; ++ii) m = fmaxf(m, v[ii]);
        m = fmaxf(m, __shfl_xor(m, 1, 64));
        m = fmaxf(m, __shfl_xor(m, 2, 64));
        float s = 0.f;
        #pragma unroll
        for (int ii = 0; ii < 16; ++ii) { v[ii] = expf(v[ii] - m); s += v[ii]; }
        s += __shfl_xor(s, 1, 64);
        s += __shfl_xor(s, 2, 64);
        const float inv = 1.f / s;
        float* wout = w_buf + (size_t)(p0 + row) * C_ + cs * 16;
        #pragma unroll
        for (int ii = 0; ii < 4; ++ii)
            *(float4*)&wout[ii * 4] = make_float4(v[ii*4] * inv, v[ii*4+1] * inv,
                                                  v[ii*4+2] * inv, v[ii*4+3] * inv);
    }
}

// ====== Phase 2: c-split x2; 256 blocks x 256 thr; thread tile 4v x 4c ======
__device__ __forceinline__ void scan_step44(float mem[4][4], float4 e4, float4 a4,
                                            float4 w4) {
    const float ev[4] = {e4.x, e4.y, e4.z, e4.w};
    const float av[4] = {a4.x, a4.y, a4.z, a4.w};
    const float wvv[4] = {w4.x, w4.y, w4.z, w4.w};
    #pragma unroll
    for (int i = 0; i < 4; ++i)
        #pragma unroll
        for (int j = 0; j < 4; ++j)
            mem[i][j] = fmaf(wvv[j], fmaf(-mem[i][j], ev[i], av[i]), mem[i][j]);
}

template<bool BF>
__device__ __forceinline__ void phase2_body(
    const void* q_emb, const void* key_memory, const void* init_value_memory,
    const int* __restrict__ target_id,
    const float* __restrict__ e_buf, const float* __restrict__ a_buf,
    const float* __restrict__ w_buf, float* __restrict__ part_buf,
    float* wtl)
{
    // b = bid&127, ch = bid>>7: both halves of batch b land on XCD (b%8)
    // (128 = 0 mod 8) -> e/a lines fetched into exactly one L2.
    const int bid = blockIdx.x;
    const int b = bid & 127;
    const int ch = bid >> 7;
    const int t = threadIdx.x;      // 0..255
    const int vg = t >> 3;          // 0..31
    const int cg = t & 7;           // 0..7
    const int v0 = vg * 4;
    const int c0 = ch * 32 + cg * 4;

    float mem[4][4];
    #pragma unroll
    for (int i = 0; i < 4; ++i) {
        const float2 m01 = ld2<BF>(init_value_memory, ((v0 + i) * C_ + c0) >> 1);
        const float2 m23 = ld2<BF>(init_value_memory, ((v0 + i) * C_ + c0 + 2) >> 1);
        mem[i][0] = m01.x; mem[i][1] = m01.y; mem[i][2] = m23.x; mem[i][3] = m23.y;
    }

    const float* eb = e_buf + (size_t)b * S_ * V_ + v0;
    const float* ab = a_buf + (size_t)b * S_ * V_ + v0;
    const float* wb = w_buf + (size_t)b * S_ * C_ + c0;

    float4 pe[5], pa[5], pw[5];
    #pragma unroll
    for (int k = 0; k < 5; ++k) {
        pe[k] = *(const float4*)(eb + (size_t)k * V_);
        pa[k] = *(const float4*)(ab + (size_t)k * V_);
        pw[k] = *(const float4*)(wb + (size_t)k * C_);
    }
    for (int s0 = 0; s0 < 195; s0 += 5) {
        #pragma unroll
        for (int k = 0; k < 5; ++k) {
            const float4 E = pe[k], A = pa[k], W = pw[k];
            const size_t sn = (size_t)(s0 + k + 5);     // <= 199
            pe[k] = *(const float4*)(eb + sn * V_);
            pa[k] = *(const float4*)(ab + sn * V_);
            pw[k] = *(const float4*)(wb + sn * C_);
            scan_step44(mem, E, A, W);
        }
    }
    #pragma unroll
    for (int k = 0; k < 5; ++k)
        scan_step44(mem, pe[k], pa[k], pw[k]);

    // wt = softmax_c(q_emb[target[b]] @ key_memory), wave 0 -> LDS (full 64 c)
    if (t < 64) {
        const long long qrow = (long long)target_id[b] * K_;
        float logit = 0.f;
        #pragma unroll 8
        for (int i = 0; i < K_; ++i)
            logit += ld<BF>(q_emb, qrow + i) * ld<BF>(key_memory, i * C_ + t);
        float m = logit;
        for (int off = 32; off > 0; off >>= 1)
            m = fmaxf(m, __shfl_xor(m, off, 64));
        const float ex = expf(logit - m);
        float ssum = ex;
        for (int off = 32; off > 0; off >>= 1)
            ssum += __shfl_xor(ssum, off, 64);
        wtl[t] = ex / ssum;
    }
    __syncthreads();

    float wt4[4];
    *(float4*)wt4 = *(const float4*)&wtl[c0];
    float red[4];
    #pragma unroll
    for (int i = 0; i < 4; ++i)
        red[i] = mem[i][0]*wt4[0] + mem[i][1]*wt4[1] + mem[i][2]*wt4[2] + mem[i][3]*wt4[3];
    #pragma unroll
    for (int off = 1; off < 8; off <<= 1) {
        #pragma unroll
        for (int i = 0; i < 4; ++i)
            red[i] += __shfl_xor(red[i], off, 64);
    }
    if (cg == 0)
        *(float4*)(part_buf + ((size_t)ch * B_ + b) * V_ + v0) =
            make_float4(red[0], red[1], red[2], red[3]);
}

__global__ __launch_bounds__(256) void dkvmn_phase2(
    const void* q_emb, const void* key_memory, const void* init_value_memory,
    const void* erase_b,
    const int* __restrict__ target_id,
    const float* e_buf, const float* a_buf, const float* w_buf,
    float* part_buf)
{
    __shared__ float wtl[C_];
    if (probe_flag_wave(erase_b))
        phase2_body<true>(q_emb, key_memory, init_value_memory, target_id,
                          e_buf, a_buf, w_buf, part_buf, wtl);
    else
        phase2_body<false>(q_emb, key_memory, init_value_memory, target_id,
                           e_buf, a_buf, w_buf, part_buf, wtl);
}

// ================= Phase 3: summ mat-vec + scalar out =================
template<bool BF>
__device__ __forceinline__ void phase3_body(
    const void* q_emb, const void* summ_W, const void* summ_b,
    const void* out_W, const void* out_b,
    const int* __restrict__ target_id, const float* __restrict__ part_buf,
    void* outp, float* summl)
{
    const int b = blockIdx.x;
    const int t = threadIdx.x;  // 0..127
    const long long qrow = (long long)target_id[b] * K_;
    const float* pb0 = part_buf + (size_t)b * V_;
    const float* pb1 = part_buf + (size_t)(B_ + b) * V_;

    float acc = ld<BF>(summ_b, t);
    #pragma unroll 8
    for (int i = 0; i < 128; ++i)
        acc += (pb0[i] + pb1[i]) * ld<BF>(summ_W, i * SUM_ + t);
    #pragma unroll 8
    for (int i = 0; i < 128; ++i)
        acc += ld<BF>(q_emb, qrow + i) * ld<BF>(summ_W, (128 + i) * SUM_ + t);
    summl[t] = tanhf(acc);
    __syncthreads();

    if (t < 64) {
        float pacc = summl[t] * ld<BF>(out_W, t) + summl[t + 64] * ld<BF>(out_W, t + 64);
        for (int off = 32; off > 0; off >>= 1)
            pacc += __shfl_xor(pacc, off, 64);
        if (t == 0) {
            const float res = pacc + ld<BF>(out_b, 0);
            if (BF) ((__hip_bfloat16*)outp)[b] = __float2bfloat16(res);
            else    ((float*)outp)[b] = res;
        }
    }
}

__global__ __launch_bounds__(128) void dkvmn_phase3(
    const void* q_emb, const void* summ_W, const void* summ_b,
    const void* out_W, const void* out_b, const void* erase_b,
    const int* __restrict__ target_id, const float* part_buf,
    void* outp)
{
    __shared__ float summl[SUM_];
    if (probe_flag_wave(erase_b))
        phase3_body<true>(q_emb, summ_W, summ_b, out_W, out_b, target_id,
                          part_buf, outp, summl);
    else
        phase3_body<false>(q_emb, summ_W, summ_b, out_W, out_b, target_id,
                           part_buf, outp, summl);
}

extern "C" void kernel_launch(void* const* d_in, const int* in_sizes, int n_in,
                              void* d_out, int out_size, void* d_ws, size_t ws_size,
                              hipStream_t stream) {
    const void* q_emb             = d_in[0];
    const void* i_emb             = d_in[1];
    const void* key_memory        = d_in[2];
    const void* init_value_memory = d_in[3];
    const void* erase_W           = d_in[4];
    const void* erase_b           = d_in[5];
    const void* add_W             = d_in[6];
    const void* add_b             = d_in[7];
    const void* summ_W            = d_in[8];
    const void* summ_b            = d_in[9];
    const void* out_W             = d_in[10];
    const void* out_b             = d_in[11];
    const int* input     = (const int*)d_in[12];
    const int* target_id = (const int*)d_in[13];

    // ws: [e B*S*V f32][a B*S*V f32][w B*S*C f32][part 2*B*V f32]
    float* e_buf    = (float*)d_ws;
    float* a_buf    = e_buf + (size_t)B_ * S_ * V_;
    float* w_buf    = a_buf + (size_t)B_ * S_ * V_;
    float* part_buf = w_buf + (size_t)B_ * S_ * C_;

    dkvmn_phase1_f32<<<(B_ * S_) / P1P, 192, 0, stream>>>(
        q_emb, i_emb, key_memory, erase_W, erase_b, add_W, add_b,
        input, e_buf, a_buf, w_buf);
    dkvmn_phase1_mfma<<<(B_ * S_) / 64, 256, 0, stream>>>(
        q_emb, i_emb, key_memory, erase_W, erase_b, add_W, add_b,
        input, e_buf, a_buf, w_buf);
    dkvmn_phase2<<<2 * B_, 256, 0, stream>>>(
        q_emb, key_memory, init_value_memory, erase_b, target_id,
        e_buf, a_buf, w_buf, part_buf);
    dkvmn_phase3<<<B_, 128, 0, stream>>>(
        q_emb, summ_W, summ_b, out_W, out_b, erase_b, target_id, part_buf, d_out);
}

// Round 9
// 149.863 us; speedup vs baseline: 1.5536x; 1.1569x over previous
//
#include <hip/hip_runtime.h>
#include <hip/hip_bf16.h>

#define B_ 128
#define S_ 200
#define QN_ 20000
#define V_ 128
#define K_ 128
#define C_ 64
#define SUM_ 128

using short8 = __attribute__((ext_vector_type(8))) short;
using f32x4  = __attribute__((ext_vector_type(4))) float;

// ---- dtype-generic loads (BF=true: bf16, BF=false: fp32) ----
template<bool BF>
__device__ __forceinline__ float ld(const void* p, long long i) {
    if (BF) return __bfloat162float(((const __hip_bfloat16*)p)[i]);
    return ((const float*)p)[i];
}
template<bool BF>
__device__ __forceinline__ float2 ld2(const void* p, long long i) {  // elems 2i, 2i+1
    if (BF) {
        __hip_bfloat162 v = ((const __hip_bfloat162*)p)[i];
        return make_float2(__bfloat162float(v.x), __bfloat162float(v.y));
    }
    return ((const float2*)p)[i];
}

__device__ __forceinline__ unsigned short f2bf(float v) {
    __hip_bfloat16 h = __float2bfloat16(v);
    unsigned short u;
    __builtin_memcpy(&u, &h, 2);
    return u;
}

// ---- dtype probe, one load/lane + ballot (wave-uniform result) ----
// r8 evidence: data is fp32 (probe=0 path live). Keep probe as insurance.
__device__ __forceinline__ int probe_flag_wave(const void* erase_b) {
    const unsigned* w = (const unsigned*)erase_b;
    const int lane = threadIdx.x & 63;
    const unsigned lo = w[lane] & 0xffffu;
    const float f = __uint_as_float(lo << 16);
    const unsigned long long bal = __ballot(!(fabsf(f) <= 0.5f));
    return (__popcll(bal) <= 8) ? 1 : 0;  // 1 = bf16
}

// ============ Prepack: weights -> bf16 MFMA B-fragments ============
// Fragment (q, wv, ks, lane) holds B[k = ks*32 + (lane>>4)*8 + jj][ncol],
// ncol = nt*16 + (lane&15), nt = wv + 4q (q: 0,1=erase_W 2,3=add_W 4=key).
// wpack index: (((q*4+wv)*4+ks)*64 + lane)*8 + jj.  5120 fragments, 80 KB.
__global__ __launch_bounds__(256) void dkvmn_prepack(
    const void* erase_W, const void* add_W, const void* key_memory,
    const void* erase_b, unsigned short* __restrict__ wpack)
{
    const int bf = probe_flag_wave(erase_b);
    const int fid = blockIdx.x * 256 + threadIdx.x;  // 0..5119
    if (fid >= 5120) return;
    const int lane = fid & 63;
    const int ks = (fid >> 6) & 3;
    const int wv = (fid >> 8) & 3;
    const int q  = fid >> 10;
    const int nt = wv + 4 * q;
    const void* Wsrc;
    int ncol, ldn;
    if (q < 2)      { Wsrc = erase_W;    ncol = nt * 16 + (lane & 15);        ldn = 128; }
    else if (q < 4) { Wsrc = add_W;      ncol = (nt - 8) * 16 + (lane & 15);  ldn = 128; }
    else            { Wsrc = key_memory; ncol = (nt - 16) * 16 + (lane & 15); ldn = 64; }
    const int k8 = (lane >> 4) * 8;
    unsigned short o[8];
    #pragma unroll
    for (int jj = 0; jj < 8; ++jj) {
        const long long idx = (long long)(ks * 32 + k8 + jj) * ldn + ncol;
        const float v = bf ? ld<true>(Wsrc, idx) : ld<false>(Wsrc, idx);
        o[jj] = f2bf(v);
    }
    *(uint4*)(wpack + (size_t)fid * 8) = *(const uint4*)o;
}

// ============ Phase 1 (MFMA, both dtypes): 64 positions/block, 4 waves ==========
// GEMM [64 x 128] @ {erase_W, add_W, key} -> 320 cols; fp32 epilogue.
// mfma_f32_16x16x32_bf16: A[m=l&15][k=(l>>4)*8+j], B[k][n=l&15],
// D: row=(l>>4)*4+reg, col=l&15.
template<bool BF>
__device__ __forceinline__ void phase1_mfma_body(
    const void* q_emb, const void* i_emb,
    const void* erase_b, const void* add_b,
    const int* __restrict__ input, const unsigned short* __restrict__ wpack,
    float* __restrict__ e_buf, float* __restrict__ a_buf, float* __restrict__ w_buf,
    unsigned short* ivA, unsigned short* qvA, float* wlog, int* sidx, int* sqid)
{
    const int p0 = blockIdx.x * 64;
    const int t = threadIdx.x;      // 0..255
    const int wv = t >> 6;          // wave 0..3
    const int lane = t & 63;
    const int lrow = lane & 15;
    const int lk8 = (lane >> 4) * 8;

    if (t < 64) {
        const int ix = input[p0 + t];
        sidx[t] = ix;
        sqid[t] = ix > QN_ ? ix - QN_ : ix;
    }
    __syncthreads();

    // stage A: 2 tensors x 64 rows x 16 segs of 8 elems (convert fp32->bf16)
    #pragma unroll
    for (int r = 0; r < 8; ++r) {
        const int j = t + 256 * r;          // 0..2047
        const int tensor = j >> 10;
        const int row = (j >> 4) & 63;
        const int seg = j & 15;
        const int gr = tensor ? sqid[row] : sidx[row];
        unsigned short* dst = (tensor ? qvA : ivA) + row * 136 + seg * 8;
        if (BF) {
            const unsigned short* src = (const unsigned short*)(tensor ? q_emb : i_emb);
            *(uint4*)dst = *(const uint4*)(src + (long long)gr * 128 + seg * 8);
        } else {
            const float* src = (const float*)(tensor ? q_emb : i_emb) + (long long)gr * 128 + seg * 8;
            const float4 f0 = *(const float4*)src;
            const float4 f1 = *(const float4*)(src + 4);
            unsigned short o[8] = {f2bf(f0.x), f2bf(f0.y), f2bf(f0.z), f2bf(f0.w),
                                   f2bf(f1.x), f2bf(f1.y), f2bf(f1.z), f2bf(f1.w)};
            *(uint4*)dst = *(const uint4*)o;
        }
    }

    // B fragments: single 16-B loads from the prepacked buffer (L2-resident)
    short8 bfr[5][4];
    int nco[5];
    float biasq[4];
    #pragma unroll
    for (int q = 0; q < 5; ++q) {
        const int nt = wv + 4 * q;
        if (q < 2)      nco[q] = nt * 16 + lrow;
        else if (q < 4) nco[q] = (nt - 8) * 16 + lrow;
        else            nco[q] = (nt - 16) * 16 + lrow;
        if (q < 2)      biasq[q] = ld<BF>(erase_b, nco[q]);
        else if (q < 4) biasq[q] = ld<BF>(add_b, nco[q]);
        #pragma unroll
        for (int ks = 0; ks < 4; ++ks)
            bfr[q][ks] = *(const short8*)(wpack +
                ((size_t)(((q * 4 + wv) * 4 + ks) * 64 + lane)) * 8);
    }
    __syncthreads();

    // IV tiles: erase (q=0,1), add (q=2,3)
    for (int mt = 0; mt < 4; ++mt) {
        short8 afr[4];
        const unsigned short* ar = ivA + (mt * 16 + lrow) * 136 + lk8;
        #pragma unroll
        for (int ks = 0; ks < 4; ++ks)
            afr[ks] = *(const short8*)(ar + ks * 32);
        #pragma unroll
        for (int q = 0; q < 4; ++q) {
            f32x4 acc = {0.f, 0.f, 0.f, 0.f};
            #pragma unroll
            for (int ks = 0; ks < 4; ++ks)
                acc = __builtin_amdgcn_mfma_f32_16x16x32_bf16(afr[ks], bfr[q][ks], acc, 0, 0, 0);
            float* dst = (q < 2) ? e_buf : a_buf;
            const int ncol = nco[q];
            const float bb = biasq[q];
            #pragma unroll
            for (int r = 0; r < 4; ++r) {
                const int prow = p0 + mt * 16 + (lane >> 4) * 4 + r;
                const float y = acc[r] + bb;
                dst[(size_t)prow * V_ + ncol] =
                    (q < 2) ? 1.f / (1.f + expf(-y)) : tanhf(y);
            }
        }
    }
    // QV key tile (q=4): logits -> LDS
    for (int mt = 0; mt < 4; ++mt) {
        short8 afr[4];
        const unsigned short* ar = qvA + (mt * 16 + lrow) * 136 + lk8;
        #pragma unroll
        for (int ks = 0; ks < 4; ++ks)
            afr[ks] = *(const short8*)(ar + ks * 32);
        f32x4 acc = {0.f, 0.f, 0.f, 0.f};
        #pragma unroll
        for (int ks = 0; ks < 4; ++ks)
            acc = __builtin_amdgcn_mfma_f32_16x16x32_bf16(afr[ks], bfr[4][ks], acc, 0, 0, 0);
        #pragma unroll
        for (int r = 0; r < 4; ++r)
            wlog[(mt * 16 + (lane >> 4) * 4 + r) * 68 + nco[4]] = acc[r];
    }
    __syncthreads();

    // softmax over 64 logits/row: thread t -> row t>>2, 16-col segment t&3
    {
        const int row = t >> 2;
        const int cs = t & 3;
        const float* wr = &wlog[row * 68 + cs * 16];
        float v[16];
        #pragma unroll
        for (int ii = 0; ii < 4; ++ii)
            *(float4*)&v[ii * 4] = *(const float4*)&wr[ii * 4];
        float m = v[0];
        #pragma unroll
        for (int ii = 1; ii < 16; ++ii) m = fmaxf(m, v[ii]);
        m = fmaxf(m, __shfl_xor(m, 1, 64));
        m = fmaxf(m, __shfl_xor(m, 2, 64));
        float s = 0.f;
        #pragma unroll
        for (int ii = 0; ii < 16; ++ii) { v[ii] = expf(v[ii] - m); s += v[ii]; }
        s += __shfl_xor(s, 1, 64);
        s += __shfl_xor(s, 2, 64);
        const float inv = 1.f / s;
        float* wout = w_buf + (size_t)(p0 + row) * C_ + cs * 16;
        #pragma unroll
        for (int ii = 0; ii < 4; ++ii)
            *(float4*)&wout[ii * 4] = make_float4(v[ii*4] * inv, v[ii*4+1] * inv,
                                                  v[ii*4+2] * inv, v[ii*4+3] * inv);
    }
}

__global__ __launch_bounds__(256) void dkvmn_phase1_mfma(
    const void* q_emb, const void* i_emb,
    const void* erase_b, const void* add_b,
    const int* __restrict__ input, const unsigned short* __restrict__ wpack,
    float* e_buf, float* a_buf, float* w_buf)
{
    __shared__ unsigned short ivA[64 * 136];  // padded rows
    __shared__ unsigned short qvA[64 * 136];
    __shared__ float wlog[64 * 68];
    __shared__ int sidx[64], sqid[64];
    if (probe_flag_wave(erase_b))
        phase1_mfma_body<true>(q_emb, i_emb, erase_b, add_b, input, wpack,
                               e_buf, a_buf, w_buf, ivA, qvA, wlog, sidx, sqid);
    else
        phase1_mfma_body<false>(q_emb, i_emb, erase_b, add_b, input, wpack,
                                e_buf, a_buf, w_buf, ivA, qvA, wlog, sidx, sqid);
}

// ====== Phase 2: c-split x2; 256 blocks x 256 thr; thread tile 4v x 4c ======
__device__ __forceinline__ void scan_step44(float mem[4][4], float4 e4, float4 a4,
                                            float4 w4) {
    const float ev[4] = {e4.x, e4.y, e4.z, e4.w};
    const float av[4] = {a4.x, a4.y, a4.z, a4.w};
    const float wvv[4] = {w4.x, w4.y, w4.z, w4.w};
    #pragma unroll
    for (int i = 0; i < 4; ++i)
        #pragma unroll
        for (int j = 0; j < 4; ++j)
            mem[i][j] = fmaf(wvv[j], fmaf(-mem[i][j], ev[i], av[i]), mem[i][j]);
}

template<bool BF>
__device__ __forceinline__ void phase2_body(
    const void* q_emb, const void* key_memory, const void* init_value_memory,
    const int* __restrict__ target_id,
    const float* __restrict__ e_buf, const float* __restrict__ a_buf,
    const float* __restrict__ w_buf, float* __restrict__ part_buf,
    float* wtl)
{
    const int bid = blockIdx.x;
    const int b = bid & 127;
    const int ch = bid >> 7;
    const int t = threadIdx.x;      // 0..255
    const int vg = t >> 3;          // 0..31
    const int cg = t & 7;           // 0..7
    const int v0 = vg * 4;
    const int c0 = ch * 32 + cg * 4;

    float mem[4][4];
    #pragma unroll
    for (int i = 0; i < 4; ++i) {
        const float2 m01 = ld2<BF>(init_value_memory, ((v0 + i) * C_ + c0) >> 1);
        const float2 m23 = ld2<BF>(init_value_memory, ((v0 + i) * C_ + c0 + 2) >> 1);
        mem[i][0] = m01.x; mem[i][1] = m01.y; mem[i][2] = m23.x; mem[i][3] = m23.y;
    }

    const float* eb = e_buf + (size_t)b * S_ * V_ + v0;
    const float* ab = a_buf + (size_t)b * S_ * V_ + v0;
    const float* wb = w_buf + (size_t)b * S_ * C_ + c0;

    float4 pe[5], pa[5], pw[5];
    #pragma unroll
    for (int k = 0; k < 5; ++k) {
        pe[k] = *(const float4*)(eb + (size_t)k * V_);
        pa[k] = *(const float4*)(ab + (size_t)k * V_);
        pw[k] = *(const float4*)(wb + (size_t)k * C_);
    }
    for (int s0 = 0; s0 < 195; s0 += 5) {
        #pragma unroll
        for (int k = 0; k < 5; ++k) {
            const float4 E = pe[k], A = pa[k], W = pw[k];
            const size_t sn = (size_t)(s0 + k + 5);     // <= 199
            pe[k] = *(const float4*)(eb + sn * V_);
            pa[k] = *(const float4*)(ab + sn * V_);
            pw[k] = *(const float4*)(wb + sn * C_);
            scan_step44(mem, E, A, W);
        }
    }
    #pragma unroll
    for (int k = 0; k < 5; ++k)
        scan_step44(mem, pe[k], pa[k], pw[k]);

    if (t < 64) {
        const long long qrow = (long long)target_id[b] * K_;
        float logit = 0.f;
        #pragma unroll 8
        for (int i = 0; i < K_; ++i)
            logit += ld<BF>(q_emb, qrow + i) * ld<BF>(key_memory, i * C_ + t);
        float m = logit;
        for (int off = 32; off > 0; off >>= 1)
            m = fmaxf(m, __shfl_xor(m, off, 64));
        const float ex = expf(logit - m);
        float ssum = ex;
        for (int off = 32; off > 0; off >>= 1)
            ssum += __shfl_xor(ssum, off, 64);
        wtl[t] = ex / ssum;
    }
    __syncthreads();

    float wt4[4];
    *(float4*)wt4 = *(const float4*)&wtl[c0];
    float red[4];
    #pragma unroll
    for (int i = 0; i < 4; ++i)
        red[i] = mem[i][0]*wt4[0] + mem[i][1]*wt4[1] + mem[i][2]*wt4[2] + mem[i][3]*wt4[3];
    #pragma unroll
    for (int off = 1; off < 8; off <<= 1) {
        #pragma unroll
        for (int i = 0; i < 4; ++i)
            red[i] += __shfl_xor(red[i], off, 64);
    }
    if (cg == 0)
        *(float4*)(part_buf + ((size_t)ch * B_ + b) * V_ + v0) =
            make_float4(red[0], red[1], red[2], red[3]);
}

__global__ __launch_bounds__(256) void dkvmn_phase2(
    const void* q_emb, const void* key_memory, const void* init_value_memory,
    const void* erase_b,
    const int* __restrict__ target_id,
    const float* e_buf, const float* a_buf, const float* w_buf,
    float* part_buf)
{
    __shared__ float wtl[C_];
    if (probe_flag_wave(erase_b))
        phase2_body<true>(q_emb, key_memory, init_value_memory, target_id,
                          e_buf, a_buf, w_buf, part_buf, wtl);
    else
        phase2_body<false>(q_emb, key_memory, init_value_memory, target_id,
                           e_buf, a_buf, w_buf, part_buf, wtl);
}

// ================= Phase 3: summ mat-vec + scalar out =================
template<bool BF>
__device__ __forceinline__ void phase3_body(
    const void* q_emb, const void* summ_W, const void* summ_b,
    const void* out_W, const void* out_b,
    const int* __restrict__ target_id, const float* __restrict__ part_buf,
    void* outp, float* summl)
{
    const int b = blockIdx.x;
    const int t = threadIdx.x;  // 0..127
    const long long qrow = (long long)target_id[b] * K_;
    const float* pb0 = part_buf + (size_t)b * V_;
    const float* pb1 = part_buf + (size_t)(B_ + b) * V_;

    float acc = ld<BF>(summ_b, t);
    #pragma unroll 8
    for (int i = 0; i < 128; ++i)
        acc += (pb0[i] + pb1[i]) * ld<BF>(summ_W, i * SUM_ + t);
    #pragma unroll 8
    for (int i = 0; i < 128; ++i)
        acc += ld<BF>(q_emb, qrow + i) * ld<BF>(summ_W, (128 + i) * SUM_ + t);
    summl[t] = tanhf(acc);
    __syncthreads();

    if (t < 64) {
        float pacc = summl[t] * ld<BF>(out_W, t) + summl[t + 64] * ld<BF>(out_W, t + 64);
        for (int off = 32; off > 0; off >>= 1)
            pacc += __shfl_xor(pacc, off, 64);
        if (t == 0) {
            const float res = pacc + ld<BF>(out_b, 0);
            if (BF) ((__hip_bfloat16*)outp)[b] = __float2bfloat16(res);
            else    ((float*)outp)[b] = res;
        }
    }
}

__global__ __launch_bounds__(128) void dkvmn_phase3(
    const void* q_emb, const void* summ_W, const void* summ_b,
    const void* out_W, const void* out_b, const void* erase_b,
    const int* __restrict__ target_id, const float* part_buf,
    void* outp)
{
    __shared__ float summl[SUM_];
    if (probe_flag_wave(erase_b))
        phase3_body<true>(q_emb, summ_W, summ_b, out_W, out_b, target_id,
                          part_buf, outp, summl);
    else
        phase3_body<false>(q_emb, summ_W, summ_b, out_W, out_b, target_id,
                           part_buf, outp, summl);
}

extern "C" void kernel_launch(void* const* d_in, const int* in_sizes, int n_in,
                              void* d_out, int out_size, void* d_ws, size_t ws_size,
                              hipStream_t stream) {
    const void* q_emb             = d_in[0];
    const void* i_emb             = d_in[1];
    const void* key_memory        = d_in[2];
    const void* init_value_memory = d_in[3];
    const void* erase_W           = d_in[4];
    const void* erase_b           = d_in[5];
    const void* add_W             = d_in[6];
    const void* add_b             = d_in[7];
    const void* summ_W            = d_in[8];
    const void* summ_b            = d_in[9];
    const void* out_W             = d_in[10];
    const void* out_b             = d_in[11];
    const int* input     = (const int*)d_in[12];
    const int* target_id = (const int*)d_in[13];

    // ws: [e B*S*V f32][a B*S*V f32][w B*S*C f32][part 2*B*V f32][wpack 80KB]
    float* e_buf    = (float*)d_ws;
    float* a_buf    = e_buf + (size_t)B_ * S_ * V_;
    float* w_buf    = a_buf + (size_t)B_ * S_ * V_;
    float* part_buf = w_buf + (size_t)B_ * S_ * C_;
    unsigned short* wpack = (unsigned short*)(part_buf + (size_t)2 * B_ * V_);

    dkvmn_prepack<<<20, 256, 0, stream>>>(erase_W, add_W, key_memory, erase_b, wpack);
    dkvmn_phase1_mfma<<<(B_ * S_) / 64, 256, 0, stream>>>(
        q_emb, i_emb, erase_b, add_b, input, wpack, e_buf, a_buf, w_buf);
    dkvmn_phase2<<<2 * B_, 256, 0, stream>>>(
        q_emb, key_memory, init_value_memory, erase_b, target_id,
        e_buf, a_buf, w_buf, part_buf);
    dkvmn_phase3<<<B_, 128, 0, stream>>>(
        q_emb, summ_W, summ_b, out_W, out_b, erase_b, target_id, part_buf, d_out);
}